// Round 8
// baseline (164.085 us; speedup 1.0000x reference)
//
#include <hip/hip_runtime.h>
#include <hip/hip_bf16.h>

#define BB 2
#define SEQ 2048
#define NHEAD 8
#define HD 64
#define ATT_T 1e-4f
#define QSCALE 0.18033688011112042f  // 0.125 * log2(e): scores in log2 domain

typedef short s16x8 __attribute__((ext_vector_type(8)));
typedef float f32x16 __attribute__((ext_vector_type(16)));

#define MFMA32(a, b, c) __builtin_amdgcn_mfma_f32_32x32x16_bf16((a), (b), (c), 0, 0, 0)
#define EXP2(x) __builtin_amdgcn_exp2f(x)
#define SB0() __builtin_amdgcn_sched_barrier(0)
// s_waitcnt imm: vmcnt[3:0]=bits3:0, expcnt=bits6:4, lgkmcnt=bits11:8, vmcnt[5:4]=bits15:14
#define WAITVM0() __builtin_amdgcn_s_waitcnt(0x0F70)
#define WAITVM4() __builtin_amdgcn_s_waitcnt(0x0F74)
#define WAITVM8() __builtin_amdgcn_s_waitcnt(0x0F78)
#define WAITVM12() __builtin_amdgcn_s_waitcnt(0x0F7C)

__device__ __forceinline__ unsigned short bfr(float x) {
  __hip_bfloat16 h = __float2bfloat16(x);
  return __builtin_bit_cast(unsigned short, h);
}
__device__ __forceinline__ unsigned int packbf(float a, float b) {
  return (unsigned int)bfr(a) | ((unsigned int)bfr(b) << 16);
}
// 1-op truncating bf16 pack of two fp32 (v_perm_b32)
__device__ __forceinline__ unsigned int permpack(float a, float b) {
  return __builtin_amdgcn_perm(__builtin_bit_cast(unsigned int, b),
                               __builtin_bit_cast(unsigned int, a), 0x07060302u);
}
__device__ __forceinline__ void async16(const void* g, void* l) {
  __builtin_amdgcn_global_load_lds(
      (const __attribute__((address_space(1))) unsigned int*)g,
      (__attribute__((address_space(3))) unsigned int*)l, 16, 0, 0);
}
// half-wave exchange: x = (lh?partner(b):a), z = (lh?b:partner(a)) in one op
__device__ __forceinline__ void plswap(unsigned a, unsigned b, int lh,
                                       unsigned& x, unsigned& z) {
#if __has_builtin(__builtin_amdgcn_permlane32_swap)
  typedef unsigned uint2v __attribute__((ext_vector_type(2)));
  uint2v r = __builtin_amdgcn_permlane32_swap(a, b, false, false);
  x = r[0];
  z = r[1];
#else
  unsigned ea = (unsigned)__shfl_xor((int)a, 32);
  unsigned eb = (unsigned)__shfl_xor((int)b, 32);
  x = lh ? eb : a;
  z = lh ? b : ea;
#endif
}

// ---------------------------------------------------------------------------
// prep: fused pre-pass (unchanged from R7, passed).
// ---------------------------------------------------------------------------
__global__ __launch_bounds__(256) void prep(const float* __restrict__ fr,
                                            const float* __restrict__ dt,
                                            const float* __restrict__ w0,
                                            const float* __restrict__ w1,
                                            const float* __restrict__ w2,
                                            const float* __restrict__ w3,
                                            unsigned short* __restrict__ frB,
                                            unsigned short* __restrict__ dtB,
                                            unsigned short* __restrict__ o0,
                                            unsigned short* __restrict__ o1,
                                            unsigned short* __restrict__ o2,
                                            unsigned short* __restrict__ o3) {
  const int bid = blockIdx.x;
  if (bid < 2048) {
    const float* src = (bid < 1024) ? fr : dt;
    unsigned short* dst = (bid < 1024) ? frB : dtB;
    const int chunk = (bid < 1024) ? bid : bid - 1024;
    const size_t base = (size_t)chunk * 2048 + threadIdx.x * 8;
    float4 a = *(const float4*)(src + base);
    float4 b = *(const float4*)(src + base + 4);
    uint4 o;
    o.x = packbf(a.x, a.y);
    o.y = packbf(a.z, a.w);
    o.z = packbf(b.x, b.y);
    o.w = packbf(b.z, b.w);
    *(uint4*)(dst + base) = o;
    return;
  }
  // ---- weight transpose tiles ----
  __shared__ float tle[64][65];
  const int t = bid - 2048;
  const int z = t >> 6, by = (t >> 3) & 7, bx = t & 7;
  const float* W = z == 0 ? w0 : z == 1 ? w1 : z == 2 ? w2 : w3;
  unsigned short* WT = z == 0 ? o0 : z == 1 ? o1 : z == 2 ? o2 : o3;
  const int r0 = by * 64, c0 = bx * 64;
  const int tr = threadIdx.x >> 4;
  const int tc = threadIdx.x & 15;
  #pragma unroll
  for (int i = 0; i < 4; i++) {
    int r = tr + i * 16;
    float4 v = *(const float4*)(W + (size_t)(r0 + r) * 512 + c0 + tc * 4);
    tle[r][tc * 4 + 0] = v.x;
    tle[r][tc * 4 + 1] = v.y;
    tle[r][tc * 4 + 2] = v.z;
    tle[r][tc * 4 + 3] = v.w;
  }
  __syncthreads();
  #pragma unroll
  for (int i = 0; i < 4; i++) {
    int c = tr + i * 16;
    int rr = tc * 4;
    uint2 p;
    p.x = packbf(tle[rr + 0][c], tle[rr + 1][c]);
    p.y = packbf(tle[rr + 2][c], tle[rr + 3][c]);
    *(uint2*)(WT + (size_t)(c0 + c) * 512 + r0 + rr) = p;
  }
}

// ---------------------------------------------------------------------------
// Fused Q/K/V projection GEMM (unchanged from R7, passed).
// ---------------------------------------------------------------------------
__global__ __launch_bounds__(256) void gemm_qkv(const unsigned short* __restrict__ frB,
                                                const unsigned short* __restrict__ dtB,
                                                const unsigned short* __restrict__ WqT,
                                                const unsigned short* __restrict__ WkT,
                                                const unsigned short* __restrict__ WvT,
                                                unsigned short* __restrict__ Qp,
                                                unsigned short* __restrict__ Kp,
                                                unsigned short* __restrict__ VTp) {
  __shared__ __align__(16) unsigned short smem[24576];  // A 2x4096 | B 2x8192 (48 KB)
  unsigned short* Asm = smem;
  unsigned short* Bsm = smem + 8192;
  const int tid = threadIdx.x, lane = tid & 63, w = tid >> 6;
  const int l31 = lane & 31, lh = lane >> 5;
  const int m0 = blockIdx.y * 64, n0 = blockIdx.x * 128;
  const int z = blockIdx.z;
  const unsigned short* Ab = z == 0 ? frB : dtB;
  const unsigned short* BT = z == 0 ? WqT : (z == 1 ? WkT : WvT);
  unsigned short* OP = z == 0 ? Qp : (z == 1 ? Kp : VTp);
  const float scale = z == 0 ? QSCALE : 1.0f;

  auto stage = [&](int kt, int buf) {
    const int k0 = kt * 64;
    #pragma unroll
    for (int i = 0; i < 2; i++) {
      int r = w * 2 + i, g = r >> 2, ks = r & 3;
      async16(Ab + (size_t)(m0 + g * 32 + l31) * 512 + k0 + ks * 16 + lh * 8,
              Asm + buf * 4096 + r * 512);
    }
    #pragma unroll
    for (int i = 0; i < 4; i++) {
      int r = w * 4 + i, gn = r >> 2, ks = r & 3;
      async16(BT + (size_t)(n0 + gn * 32 + l31) * 512 + k0 + ks * 16 + lh * 8,
              Bsm + buf * 8192 + r * 512);
    }
  };

  f32x16 acc[2];
  #pragma unroll
  for (int j = 0; j < 2; j++)
    #pragma unroll
    for (int r = 0; r < 16; r++) acc[j][r] = 0.f;

  stage(0, 0);
  for (int kt = 0; kt < 8; ++kt) {
    __syncthreads();
    if (kt + 1 < 8) stage(kt + 1, (kt + 1) & 1);
    const int buf = kt & 1;
    const unsigned short* as = Asm + buf * 4096 + (w & 1) * 2048;
    const unsigned short* bs = Bsm + buf * 8192 + (w >> 1) * 4096;
    #pragma unroll
    for (int ks = 0; ks < 4; ++ks) {
      s16x8 af = *(const s16x8*)(as + ks * 512 + lane * 8);
      s16x8 b0 = *(const s16x8*)(bs + ks * 512 + lane * 8);
      s16x8 b1 = *(const s16x8*)(bs + 2048 + ks * 512 + lane * 8);
      acc[0] = MFMA32(af, b0, acc[0]);
      acc[1] = MFMA32(af, b1, acc[1]);
    }
  }

  const int wm = (w & 1) * 32, wn = (w >> 1) * 64;
  const int bb = m0 >> 11, s0 = m0 & 2047;
  __syncthreads();
  if (z <= 1) {
    #pragma unroll
    for (int j = 0; j < 2; j++)
      #pragma unroll
      for (int r = 0; r < 16; r++) {
        int mm = wm + (r & 3) + 8 * (r >> 2) + 4 * lh;
        int nn = wn + j * 32 + l31;
        smem[mm * 136 + nn] = bfr(acc[j][r] * scale);
      }
    __syncthreads();
    #pragma unroll
    for (int it = 0; it < 4; ++it) {
      int c = tid + it * 256;
      int mm = c >> 4, seg = c & 15;
      uint4 vdat = *(const uint4*)(smem + mm * 136 + seg * 8);
      int n = n0 + seg * 8, h = n >> 6, d = n & 63;
      *(uint4*)(OP + ((size_t)((bb * NHEAD + h) * SEQ + s0 + mm)) * HD + d) = vdat;
    }
  } else {
    #pragma unroll
    for (int j = 0; j < 2; j++)
      #pragma unroll
      for (int r = 0; r < 16; r += 2) {
        int mm = wm + (r & 3) + 8 * (r >> 2) + 4 * lh;  // even
        int nn = wn + j * 32 + l31;
        *(unsigned int*)(smem + nn * 72 + mm) = packbf(acc[j][r], acc[j][r + 1]);
      }
    __syncthreads();
    #pragma unroll
    for (int it = 0; it < 4; ++it) {
      int c = tid + it * 256;
      int nn = c >> 3, seg = c & 7;
      uint4 vdat = *(const uint4*)(smem + nn * 72 + seg * 8);
      int n = n0 + nn, h = n >> 6, d = n & 63;
      *(uint4*)(OP + ((size_t)((bb * NHEAD + h) * HD + d)) * SEQ + s0 + seg * 8) = vdat;
    }
  }
}

// ---------------------------------------------------------------------------
// Final projection: out[4096,512] = aoB @ WoT^T + bias, fp32 out (unchanged).
// ---------------------------------------------------------------------------
__global__ __launch_bounds__(256) void gemm_out(const unsigned short* __restrict__ A,
                                                const unsigned short* __restrict__ BT,
                                                const float* __restrict__ bias,
                                                float* __restrict__ O) {
  __shared__ __align__(16) unsigned short smem[16384];  // A 2x4096 | B 2x4096
  unsigned short* Asm = smem;
  unsigned short* Bsm = smem + 8192;
  const int tid = threadIdx.x, lane = tid & 63, w = tid >> 6;
  const int l31 = lane & 31, lh = lane >> 5;
  const int m0 = blockIdx.y * 64, n0 = blockIdx.x * 64;

  auto stage = [&](int kt, int buf) {
    const int k0 = kt * 64;
    #pragma unroll
    for (int i = 0; i < 2; i++) {
      int r = w * 2 + i, g = r >> 2, ks = r & 3;
      async16(A + (size_t)(m0 + g * 32 + l31) * 512 + k0 + ks * 16 + lh * 8,
              Asm + buf * 4096 + r * 512);
      async16(BT + (size_t)(n0 + g * 32 + l31) * 512 + k0 + ks * 16 + lh * 8,
              Bsm + buf * 4096 + r * 512);
    }
  };

  f32x16 acc;
  #pragma unroll
  for (int r = 0; r < 16; r++) acc[r] = 0.f;

  stage(0, 0);
  for (int kt = 0; kt < 8; ++kt) {
    __syncthreads();
    if (kt + 1 < 8) stage(kt + 1, (kt + 1) & 1);
    const int buf = kt & 1;
    const unsigned short* as = Asm + buf * 4096 + (w & 1) * 2048;
    const unsigned short* bs = Bsm + buf * 4096 + (w >> 1) * 2048;
    #pragma unroll
    for (int ks = 0; ks < 4; ++ks) {
      s16x8 af = *(const s16x8*)(as + ks * 512 + lane * 8);
      s16x8 bf = *(const s16x8*)(bs + ks * 512 + lane * 8);
      acc = MFMA32(af, bf, acc);
    }
  }

  const int wm = (w & 1) * 32, wn = (w >> 1) * 32;
  float bv = bias[n0 + wn + l31];
  #pragma unroll
  for (int r = 0; r < 16; r++) {
    int mm = wm + (r & 3) + 8 * (r >> 2) + 4 * lh;
    O[(size_t)(m0 + mm) * 512 + n0 + wn + l31] = acc[r] + bv;
  }
}

// ---------------------------------------------------------------------------
// MFMA flash attention — R8: deep-prefetch pipeline. K in a 4-slot LDS ring
// (prefetch depth 3 ~ 1100+ cy > 900 cy cold-HBM latency; L2 is thrashed
// between dispatches by the harness's memsets, so K/V are HBM-cold each
// iteration — FETCH_SIZE 6.3 MB/dispatch proves it). V stays in 2-deep reg
// dbuf (consumption distance ~1200 cy already). Sweep 2 uses ONE counted
// vmcnt(12) per half-chunk, draining exactly {K(i), V(i-1)} while 3 K-chunks
// + 1 V-chunk stay in flight; never drains to 0 mid-loop (T3/T4).
// Queue trace (steady, per half-iter issues [V(i+1), K(i+3)]):
//   at wait: [K(i),V(i-1),K(i+1),V(i),K(i+2)]=20 -> vmcnt(12) completes
//   K(i),V(i-1). Prologue: cc=0 even VM12 (drains K0..K2), cc=0 odd VM8
//   (drains V0). Epilogue: cc=14 even VM8, odd VM4, final VM0.
// LDS 66 KB -> still 2 blocks/CU. 512 blocks x 4 waves, 64 q/wave (R5 shape).
// ---------------------------------------------------------------------------
__global__ __launch_bounds__(256, 2) void attn_mfma(const unsigned short* __restrict__ Q,
                                                    const unsigned short* __restrict__ K,
                                                    const unsigned short* __restrict__ VT,
                                                    unsigned short* __restrict__ O) {
  __shared__ __align__(16) unsigned short arena[4][8192];  // 16 KB/wave: K 4-slot ring
  __shared__ float larr[4][64];
  __shared__ float warr[4][64];

  const int tid = threadIdx.x;
  const int lane = tid & 63;
  const int w = tid >> 6;          // wave id = key quarter
  const int l31 = lane & 31, lh = lane >> 5;

  // XCD swizzle: pin 2 bh per XCD
  const int bid = blockIdx.x;
  const int g = bid & 7, j = bid >> 3;   // j in [0,64)
  const int bh = g * 2 + (j >> 5);
  const int qt = j & 31;                 // 32 q-tiles of 64 rows

  const unsigned short* Qh = Q + (size_t)bh * SEQ * HD;
  const unsigned short* Kh = K + (size_t)bh * SEQ * HD;
  const unsigned short* VTh = VT + (size_t)bh * HD * SEQ;

  s16x8 qf[2][4];
  #pragma unroll
  for (int q2 = 0; q2 < 2; q2++)
    #pragma unroll
    for (int t = 0; t < 4; t++)
      qf[q2][t] = *(const s16x8*)(Qh + (size_t)(qt * 64 + q2 * 32 + l31) * HD + 16 * t + 8 * lh);

  unsigned short* kbuf = &arena[w][0];  // 4 slots x 2048 ushorts
  const int kbase = w * 512;

  auto stageK = [&](int c, int slot) {
    const unsigned short* base = Kh + (size_t)(kbase + c * 32 + l31) * HD + lh * 8;
    #pragma unroll
    for (int tt = 0; tt < 4; tt++)
      async16(base + tt * 16, kbuf + slot * 2048 + tt * 512);
  };

  f32x16 scp[2];
  auto qkt = [&](int slot) {
    s16x8 kf[4];
    #pragma unroll
    for (int tt = 0; tt < 4; tt++)
      kf[tt] = *(const s16x8*)(kbuf + slot * 2048 + tt * 512 + lane * 8);
    #pragma unroll
    for (int q2 = 0; q2 < 2; q2++) {
      f32x16 sc;
      #pragma unroll
      for (int r = 0; r < 16; r++) sc[r] = 0.f;
      #pragma unroll
      for (int tt = 0; tt < 4; tt++) sc = MFMA32(kf[tt], qf[q2][tt], sc);
      scp[q2] = sc;
    }
  };

  // ---------------- sweep 1: per-q l = sum(exp2(s)), 4-deep pipeline -----
  float lsum[2] = {0.f, 0.f};
  auto accum_l = [&]() {
    #pragma unroll
    for (int q2 = 0; q2 < 2; q2++) {
      float s0 = 0.f, s1 = 0.f, s2 = 0.f, s3 = 0.f;
      #pragma unroll
      for (int r = 0; r < 4; r++) {
        s0 += EXP2(scp[q2][r]);
        s1 += EXP2(scp[q2][4 + r]);
        s2 += EXP2(scp[q2][8 + r]);
        s3 += EXP2(scp[q2][12 + r]);
      }
      lsum[q2] += (s0 + s1) + (s2 + s3);
    }
  };

  stageK(0, 0);
  stageK(1, 1);
  stageK(2, 2);
  for (int c = 0; c < 16; ++c) {
    if (c + 3 < 16) stageK(c + 3, (c + 3) & 3);
    if (c > 0) accum_l();
    if (c < 13) { WAITVM12(); }
    else if (c == 13) { WAITVM8(); }
    else if (c == 14) { WAITVM4(); }
    else { WAITVM0(); }
    SB0();
    qkt(c & 3);
  }
  accum_l();
  #pragma unroll
  for (int q2 = 0; q2 < 2; q2++) lsum[q2] += __shfl_xor(lsum[q2], 32);
  if (lh == 0) { larr[w][l31] = lsum[0]; larr[w][32 + l31] = lsum[1]; }
  __syncthreads();
  float tl[2];
  #pragma unroll
  for (int q2 = 0; q2 < 2; q2++)
    tl[q2] = ATT_T * (larr[0][q2 * 32 + l31] + larr[1][q2 * 32 + l31] +
                      larr[2][q2 * 32 + l31] + larr[3][q2 * 32 + l31]);

  // ---------------- sweep 2: clip + PV, 4-deep K + 2-deep V ----------------
  f32x16 acc[2][2];
  #pragma unroll
  for (int q2 = 0; q2 < 2; q2++)
    #pragma unroll
    for (int dh = 0; dh < 2; dh++)
      #pragma unroll
      for (int r = 0; r < 16; r++) acc[q2][dh][r] = 0.f;
  float wacc[2] = {0.f, 0.f};
  s16x8 vrA[4], vrB[4];  // V dbuf in regs, statically indexed

  auto loadV = [&](int c, s16x8(&vr)[4]) {
    #pragma unroll
    for (int dh = 0; dh < 2; dh++)
      #pragma unroll
      for (int kc = 0; kc < 2; kc++)
        vr[dh * 2 + kc] = *(const s16x8*)(VTh + (size_t)(dh * 32 + l31) * SEQ +
                                          kbase + c * 32 + kc * 16 + lh * 8);
  };
  auto softmax_pv = [&](const s16x8(&vr)[4]) {
    s16x8 pf[2][2];
    #pragma unroll
    for (int q2 = 0; q2 < 2; q2++) {
      uint2 quads[4];
      #pragma unroll
      for (int gq = 0; gq < 4; gq++) {
        float u0 = fmaxf(EXP2(scp[q2][4 * gq + 0]) - tl[q2], 0.f);
        float u1 = fmaxf(EXP2(scp[q2][4 * gq + 1]) - tl[q2], 0.f);
        float u2 = fmaxf(EXP2(scp[q2][4 * gq + 2]) - tl[q2], 0.f);
        float u3 = fmaxf(EXP2(scp[q2][4 * gq + 3]) - tl[q2], 0.f);
        wacc[q2] += (u0 + u1) + (u2 + u3);
        quads[gq].x = permpack(u0, u1);
        quads[gq].y = permpack(u2, u3);
      }
      #pragma unroll
      for (int tp = 0; tp < 2; tp++) {
        unsigned x0, z0, x1, z1;
        plswap(quads[2 * tp].x, quads[2 * tp + 1].x, lh, x0, z0);
        plswap(quads[2 * tp].y, quads[2 * tp + 1].y, lh, x1, z1);
        uint4 fr;
        fr.x = x0; fr.y = x1; fr.z = z0; fr.w = z1;
        pf[q2][tp] = __builtin_bit_cast(s16x8, fr);
      }
    }
    #pragma unroll
    for (int q2 = 0; q2 < 2; q2++)
      #pragma unroll
      for (int dh = 0; dh < 2; dh++) {
        acc[q2][dh] = MFMA32(pf[q2][0], vr[dh * 2 + 0], acc[q2][dh]);
        acc[q2][dh] = MFMA32(pf[q2][1], vr[dh * 2 + 1], acc[q2][dh]);
      }
  };

  stageK(0, 0);
  stageK(1, 1);
  stageK(2, 2);
  loadV(0, vrA);
  for (int cc = 0; cc < 16; cc += 2) {
    // -------- even half i=cc: softmax chunk cc-1 (vrB), qkt(cc) --------
    if (cc > 0) {
      if (cc < 14) { WAITVM12(); } else { WAITVM8(); }
      SB0();
      softmax_pv(vrB);                  // chunk cc-1, uses V(cc-1)
    }
    loadV(cc + 1, vrB);
    if (cc + 3 < 16) stageK(cc + 3, (cc + 3) & 3);
    if (cc == 0) { WAITVM12(); }        // cold start: drains K0..K2
    SB0();
    qkt(cc & 3);
    // -------- odd half i=cc+1: softmax chunk cc (vrA), qkt(cc+1) --------
    if (cc == 0) { WAITVM8(); }         // drains V0
    else if (cc < 14) { WAITVM12(); }
    else { WAITVM4(); }
    SB0();
    softmax_pv(vrA);                    // chunk cc, uses V(cc)
    if (cc + 2 < 16) loadV(cc + 2, vrA);
    if (cc + 4 < 16) stageK(cc + 4, (cc + 4) & 3);
    SB0();
    qkt((cc + 1) & 3);
  }
  WAITVM0();
  SB0();
  softmax_pv(vrB);                      // chunk 15, uses V(15)

  // ---------------- cross-wave merge + output ----------------
  #pragma unroll
  for (int q2 = 0; q2 < 2; q2++) wacc[q2] += __shfl_xor(wacc[q2], 32);
  if (lh == 0) { warr[w][l31] = wacc[0]; warr[w][32 + l31] = wacc[1]; }
  __syncthreads();

  float* plane0 = (float*)&arena[0][0];  // 64x64 f32 = 16 KB (row 0)
  float* plane1 = (float*)&arena[1][0];  // row 1

  if (w >= 2) {
    float* pl = (w == 2) ? plane0 : plane1;
    #pragma unroll
    for (int q2 = 0; q2 < 2; q2++)
      #pragma unroll
      for (int dh = 0; dh < 2; dh++)
        #pragma unroll
        for (int r = 0; r < 16; r++) {
          int ql = q2 * 32 + (r & 3) + 8 * (r >> 2) + 4 * lh;
          pl[ql * 64 + dh * 32 + l31] = acc[q2][dh][r];
        }
  }
  __syncthreads();
  if (w < 2) {
    float* pl = (w == 0) ? plane0 : plane1;
    #pragma unroll
    for (int q2 = 0; q2 < 2; q2++)
      #pragma unroll
      for (int dh = 0; dh < 2; dh++)
        #pragma unroll
        for (int r = 0; r < 16; r++) {
          int ql = q2 * 32 + (r & 3) + 8 * (r >> 2) + 4 * lh;
          acc[q2][dh][r] += pl[ql * 64 + dh * 32 + l31];
        }
  }
  __syncthreads();
  if (w == 1) {
    #pragma unroll
    for (int q2 = 0; q2 < 2; q2++)
      #pragma unroll
      for (int dh = 0; dh < 2; dh++)
        #pragma unroll
        for (int r = 0; r < 16; r++) {
          int ql = q2 * 32 + (r & 3) + 8 * (r >> 2) + 4 * lh;
          plane0[ql * 64 + dh * 32 + l31] = acc[q2][dh][r];
        }
  }
  __syncthreads();
  unsigned short* otile = &arena[2][0];  // 64x64 bf16 = 8 KB (row 2)
  if (w == 0) {
    #pragma unroll
    for (int q2 = 0; q2 < 2; q2++)
      #pragma unroll
      for (int dh = 0; dh < 2; dh++)
        #pragma unroll
        for (int r = 0; r < 16; r++) {
          int ql = q2 * 32 + (r & 3) + 8 * (r >> 2) + 4 * lh;
          float wt = warr[0][ql] + warr[1][ql] + warr[2][ql] + warr[3][ql];
          float v = (acc[q2][dh][r] + plane0[ql * 64 + dh * 32 + l31]) / wt;
          otile[ql * 64 + dh * 32 + l31] = bfr(v);
        }
  }
  __syncthreads();
  const int b = bh >> 3, h = bh & 7;
  #pragma unroll
  for (int it = 0; it < 2; ++it) {
    int c2 = tid + it * 256;
    int mm = c2 >> 3, seg = c2 & 7;
    uint4 vdat = *(const uint4*)(otile + mm * 64 + seg * 8);
    *(uint4*)(O + ((size_t)(b * SEQ + qt * 64 + mm)) * 512 + h * HD + seg * 8) = vdat;
  }
}

// ---------------------------------------------------------------------------
extern "C" void kernel_launch(void* const* d_in, const int* in_sizes, int n_in,
                              void* d_out, int out_size, void* d_ws, size_t ws_size,
                              hipStream_t stream) {
  const float* fr = (const float*)d_in[0];
  const float* dt = (const float*)d_in[1];
  const float* Wq = (const float*)d_in[2];
  const float* Wk = (const float*)d_in[3];
  const float* Wv = (const float*)d_in[4];
  const float* Wo = (const float*)d_in[5];
  const float* bo = (const float*)d_in[6];
  float* out = (float*)d_out;

  const size_t planeE = (size_t)BB * SEQ * 512;  // 2,097,152 elements
  const size_t wE = 512 * 512;
  unsigned short* p = (unsigned short*)d_ws;
  unsigned short* WqT = p; p += wE;
  unsigned short* WkT = p; p += wE;
  unsigned short* WvT = p; p += wE;
  unsigned short* WoT = p; p += wE;
  unsigned short* Qp  = p; p += planeE;
  unsigned short* Kp  = p; p += planeE;
  unsigned short* VTp = p; p += planeE;
  unsigned short* aoB = p; p += planeE;

  // bf16 copies of fr/dt live in d_out (8.4 MB = exactly out_size); they are
  // fully consumed by gemm_qkv before gemm_out overwrites d_out with the
  // final fp32 result.
  unsigned short* frB = (unsigned short*)d_out;
  unsigned short* dtB = (unsigned short*)d_out + planeE;

  prep<<<2304, 256, 0, stream>>>(fr, dt, Wq, Wk, Wv, Wo, frB, dtB, WqT, WkT, WvT, WoT);

  gemm_qkv<<<dim3(4, 64, 3), 256, 0, stream>>>(frB, dtB, WqT, WkT, WvT, Qp, Kp, VTp);

  attn_mfma<<<BB * NHEAD * 32, 256, 0, stream>>>(Qp, Kp, VTp, aoB);

  gemm_out<<<dim3(8, 64), 256, 0, stream>>>(aoB, WoT, bo, out);
}

// Round 9
// 143.212 us; speedup vs baseline: 1.1457x; 1.1457x over previous
//
#include <hip/hip_runtime.h>
#include <hip/hip_bf16.h>

#define BB 2
#define SEQ 2048
#define NHEAD 8
#define HD 64
#define ATT_T 1e-4f
#define QSCALE 0.18033688011112042f  // 0.125 * log2(e): scores in log2 domain

typedef short s16x8 __attribute__((ext_vector_type(8)));
typedef float f32x16 __attribute__((ext_vector_type(16)));

#define MFMA32(a, b, c) __builtin_amdgcn_mfma_f32_32x32x16_bf16((a), (b), (c), 0, 0, 0)
#define EXP2(x) __builtin_amdgcn_exp2f(x)
#define SB0() __builtin_amdgcn_sched_barrier(0)
// s_waitcnt imm: vmcnt[3:0]=bits3:0, expcnt=bits6:4, lgkmcnt=bits11:8, vmcnt[5:4]=bits15:14
#define WAITVM0() __builtin_amdgcn_s_waitcnt(0x0F70)
#define WAITVM4() __builtin_amdgcn_s_waitcnt(0x0F74)
#define WAITVM8() __builtin_amdgcn_s_waitcnt(0x0F78)
#define WAITVM12() __builtin_amdgcn_s_waitcnt(0x0F7C)

__device__ __forceinline__ unsigned short bfr(float x) {
  __hip_bfloat16 h = __float2bfloat16(x);
  return __builtin_bit_cast(unsigned short, h);
}
__device__ __forceinline__ unsigned int packbf(float a, float b) {
  return (unsigned int)bfr(a) | ((unsigned int)bfr(b) << 16);
}
// 1-op truncating bf16 pack of two fp32 (v_perm_b32)
__device__ __forceinline__ unsigned int permpack(float a, float b) {
  return __builtin_amdgcn_perm(__builtin_bit_cast(unsigned int, b),
                               __builtin_bit_cast(unsigned int, a), 0x07060302u);
}
__device__ __forceinline__ void async16(const void* g, void* l) {
  __builtin_amdgcn_global_load_lds(
      (const __attribute__((address_space(1))) unsigned int*)g,
      (__attribute__((address_space(3))) unsigned int*)l, 16, 0, 0);
}
// half-wave exchange: x = (lh?partner(b):a), z = (lh?b:partner(a)) in one op
__device__ __forceinline__ void plswap(unsigned a, unsigned b, int lh,
                                       unsigned& x, unsigned& z) {
#if __has_builtin(__builtin_amdgcn_permlane32_swap)
  typedef unsigned uint2v __attribute__((ext_vector_type(2)));
  uint2v r = __builtin_amdgcn_permlane32_swap(a, b, false, false);
  x = r[0];
  z = r[1];
#else
  unsigned ea = (unsigned)__shfl_xor((int)a, 32);
  unsigned eb = (unsigned)__shfl_xor((int)b, 32);
  x = lh ? eb : a;
  z = lh ? b : ea;
#endif
}

// ---------------------------------------------------------------------------
// R9 staging scheme (T2 / G4): tiles whose rows are 128B (64 bf16) are staged
// with ONE async16 per 8-row stripe: lane u reads global
//   row = stripe*8 + (u>>3), 16B-unit col = (u&7) ^ (u>>3)   [XOR swizzle]
// -> 1KB CONTIGUOUS per instruction (16 fully-used 64B txn vs 32 half-used
// before). LDS dest stays linear (rule #21); fragment ds_read_b128 applies
// the same XOR: addr = row*64 + ((col16 ^ (row&7)) * 8) shorts -> per-8-lane
// group the permuted units cover all 32 banks once = conflict-free.
// ---------------------------------------------------------------------------

// ---------------------------------------------------------------------------
// prep: fused pre-pass (unchanged, passed).
// ---------------------------------------------------------------------------
__global__ __launch_bounds__(256) void prep(const float* __restrict__ fr,
                                            const float* __restrict__ dt,
                                            const float* __restrict__ w0,
                                            const float* __restrict__ w1,
                                            const float* __restrict__ w2,
                                            const float* __restrict__ w3,
                                            unsigned short* __restrict__ frB,
                                            unsigned short* __restrict__ dtB,
                                            unsigned short* __restrict__ o0,
                                            unsigned short* __restrict__ o1,
                                            unsigned short* __restrict__ o2,
                                            unsigned short* __restrict__ o3) {
  const int bid = blockIdx.x;
  if (bid < 2048) {
    const float* src = (bid < 1024) ? fr : dt;
    unsigned short* dst = (bid < 1024) ? frB : dtB;
    const int chunk = (bid < 1024) ? bid : bid - 1024;
    const size_t base = (size_t)chunk * 2048 + threadIdx.x * 8;
    float4 a = *(const float4*)(src + base);
    float4 b = *(const float4*)(src + base + 4);
    uint4 o;
    o.x = packbf(a.x, a.y);
    o.y = packbf(a.z, a.w);
    o.z = packbf(b.x, b.y);
    o.w = packbf(b.z, b.w);
    *(uint4*)(dst + base) = o;
    return;
  }
  // ---- weight transpose tiles ----
  __shared__ float tle[64][65];
  const int t = bid - 2048;
  const int z = t >> 6, by = (t >> 3) & 7, bx = t & 7;
  const float* W = z == 0 ? w0 : z == 1 ? w1 : z == 2 ? w2 : w3;
  unsigned short* WT = z == 0 ? o0 : z == 1 ? o1 : z == 2 ? o2 : o3;
  const int r0 = by * 64, c0 = bx * 64;
  const int tr = threadIdx.x >> 4;
  const int tc = threadIdx.x & 15;
  #pragma unroll
  for (int i = 0; i < 4; i++) {
    int r = tr + i * 16;
    float4 v = *(const float4*)(W + (size_t)(r0 + r) * 512 + c0 + tc * 4);
    tle[r][tc * 4 + 0] = v.x;
    tle[r][tc * 4 + 1] = v.y;
    tle[r][tc * 4 + 2] = v.z;
    tle[r][tc * 4 + 3] = v.w;
  }
  __syncthreads();
  #pragma unroll
  for (int i = 0; i < 4; i++) {
    int c = tr + i * 16;
    int rr = tc * 4;
    uint2 p;
    p.x = packbf(tle[rr + 0][c], tle[rr + 1][c]);
    p.y = packbf(tle[rr + 2][c], tle[rr + 3][c]);
    *(uint2*)(WT + (size_t)(c0 + c) * 512 + r0 + rr) = p;
  }
}

// ---------------------------------------------------------------------------
// Fused Q/K/V projection GEMM — R9: coalesced-swizzled staging (see header).
// LDS layout now row-major [row][64] with per-row XOR; fragment reads carry
// the matching XOR. MFMA math identical.
// ---------------------------------------------------------------------------
__global__ __launch_bounds__(256) void gemm_qkv(const unsigned short* __restrict__ frB,
                                                const unsigned short* __restrict__ dtB,
                                                const unsigned short* __restrict__ WqT,
                                                const unsigned short* __restrict__ WkT,
                                                const unsigned short* __restrict__ WvT,
                                                unsigned short* __restrict__ Qp,
                                                unsigned short* __restrict__ Kp,
                                                unsigned short* __restrict__ VTp) {
  __shared__ __align__(16) unsigned short smem[24576];  // A 2x4096 | B 2x8192 (48 KB)
  unsigned short* Asm = smem;
  unsigned short* Bsm = smem + 8192;
  const int tid = threadIdx.x, lane = tid & 63, w = tid >> 6;
  const int l31 = lane & 31, lh = lane >> 5;
  const int m0 = blockIdx.y * 64, n0 = blockIdx.x * 128;
  const int z = blockIdx.z;
  const unsigned short* Ab = z == 0 ? frB : dtB;
  const unsigned short* BT = z == 0 ? WqT : (z == 1 ? WkT : WvT);
  unsigned short* OP = z == 0 ? Qp : (z == 1 ? Kp : VTp);
  const float scale = z == 0 ? QSCALE : 1.0f;

  const int rl = lane >> 3;                       // row within stripe
  const int cl8 = ((lane & 7) ^ rl) * 8;          // swizzled 16B-unit, in shorts
  const int x7 = l31 & 7;

  auto stage = [&](int kt, int buf) {
    const int k0 = kt * 64;
    #pragma unroll
    for (int i = 0; i < 2; i++) {
      int s = w * 2 + i;                          // A stripe 0..7 (64 rows)
      async16(Ab + (size_t)(m0 + s * 8 + rl) * 512 + k0 + cl8,
              Asm + buf * 4096 + s * 512);
    }
    #pragma unroll
    for (int i = 0; i < 4; i++) {
      int s = w * 4 + i;                          // B stripe 0..15 (128 rows)
      async16(BT + (size_t)(n0 + s * 8 + rl) * 512 + k0 + cl8,
              Bsm + buf * 8192 + s * 512);
    }
  };

  f32x16 acc[2];
  #pragma unroll
  for (int j = 0; j < 2; j++)
    #pragma unroll
    for (int r = 0; r < 16; r++) acc[j][r] = 0.f;

  stage(0, 0);
  for (int kt = 0; kt < 8; ++kt) {
    __syncthreads();
    if (kt + 1 < 8) stage(kt + 1, (kt + 1) & 1);
    const int buf = kt & 1;
    const unsigned short* as = Asm + buf * 4096 + ((w & 1) * 32 + l31) * 64;
    const unsigned short* bs = Bsm + buf * 8192 + ((w >> 1) * 64 + l31) * 64;
    #pragma unroll
    for (int ks = 0; ks < 4; ++ks) {
      const int co = ((ks * 2 + lh) ^ x7) * 8;
      s16x8 af = *(const s16x8*)(as + co);
      s16x8 b0 = *(const s16x8*)(bs + co);
      s16x8 b1 = *(const s16x8*)(bs + 2048 + co);
      acc[0] = MFMA32(af, b0, acc[0]);
      acc[1] = MFMA32(af, b1, acc[1]);
    }
  }

  const int wm = (w & 1) * 32, wn = (w >> 1) * 64;
  const int bb = m0 >> 11, s0 = m0 & 2047;
  __syncthreads();
  if (z <= 1) {
    #pragma unroll
    for (int j = 0; j < 2; j++)
      #pragma unroll
      for (int r = 0; r < 16; r++) {
        int mm = wm + (r & 3) + 8 * (r >> 2) + 4 * lh;
        int nn = wn + j * 32 + l31;
        smem[mm * 136 + nn] = bfr(acc[j][r] * scale);
      }
    __syncthreads();
    #pragma unroll
    for (int it = 0; it < 4; ++it) {
      int c = tid + it * 256;
      int mm = c >> 4, seg = c & 15;
      uint4 vdat = *(const uint4*)(smem + mm * 136 + seg * 8);
      int n = n0 + seg * 8, h = n >> 6, d = n & 63;
      *(uint4*)(OP + ((size_t)((bb * NHEAD + h) * SEQ + s0 + mm)) * HD + d) = vdat;
    }
  } else {
    #pragma unroll
    for (int j = 0; j < 2; j++)
      #pragma unroll
      for (int r = 0; r < 16; r += 2) {
        int mm = wm + (r & 3) + 8 * (r >> 2) + 4 * lh;  // even
        int nn = wn + j * 32 + l31;
        *(unsigned int*)(smem + nn * 72 + mm) = packbf(acc[j][r], acc[j][r + 1]);
      }
    __syncthreads();
    #pragma unroll
    for (int it = 0; it < 4; ++it) {
      int c = tid + it * 256;
      int nn = c >> 3, seg = c & 7;
      uint4 vdat = *(const uint4*)(smem + nn * 72 + seg * 8);
      int n = n0 + nn, h = n >> 6, d = n & 63;
      *(uint4*)(OP + ((size_t)((bb * NHEAD + h) * HD + d)) * SEQ + s0 + seg * 8) = vdat;
    }
  }
}

// ---------------------------------------------------------------------------
// Final projection — R9: same coalesced-swizzled staging (A,B 64x64 tiles).
// ---------------------------------------------------------------------------
__global__ __launch_bounds__(256) void gemm_out(const unsigned short* __restrict__ A,
                                                const unsigned short* __restrict__ BT,
                                                const float* __restrict__ bias,
                                                float* __restrict__ O) {
  __shared__ __align__(16) unsigned short smem[16384];  // A 2x4096 | B 2x4096
  unsigned short* Asm = smem;
  unsigned short* Bsm = smem + 8192;
  const int tid = threadIdx.x, lane = tid & 63, w = tid >> 6;
  const int l31 = lane & 31, lh = lane >> 5;
  const int m0 = blockIdx.y * 64, n0 = blockIdx.x * 64;

  const int rl = lane >> 3;
  const int cl8 = ((lane & 7) ^ rl) * 8;
  const int x7 = l31 & 7;

  auto stage = [&](int kt, int buf) {
    const int k0 = kt * 64;
    #pragma unroll
    for (int i = 0; i < 2; i++) {
      int s = w * 2 + i;
      async16(A + (size_t)(m0 + s * 8 + rl) * 512 + k0 + cl8,
              Asm + buf * 4096 + s * 512);
      async16(BT + (size_t)(n0 + s * 8 + rl) * 512 + k0 + cl8,
              Bsm + buf * 4096 + s * 512);
    }
  };

  f32x16 acc;
  #pragma unroll
  for (int r = 0; r < 16; r++) acc[r] = 0.f;

  stage(0, 0);
  for (int kt = 0; kt < 8; ++kt) {
    __syncthreads();
    if (kt + 1 < 8) stage(kt + 1, (kt + 1) & 1);
    const int buf = kt & 1;
    const unsigned short* as = Asm + buf * 4096 + ((w & 1) * 32 + l31) * 64;
    const unsigned short* bs = Bsm + buf * 4096 + ((w >> 1) * 32 + l31) * 64;
    #pragma unroll
    for (int ks = 0; ks < 4; ++ks) {
      const int co = ((ks * 2 + lh) ^ x7) * 8;
      s16x8 af = *(const s16x8*)(as + co);
      s16x8 bf = *(const s16x8*)(bs + co);
      acc = MFMA32(af, bf, acc);
    }
  }

  const int wm = (w & 1) * 32, wn = (w >> 1) * 32;
  float bv = bias[n0 + wn + l31];
  #pragma unroll
  for (int r = 0; r < 16; r++) {
    int mm = wm + (r & 3) + 8 * (r >> 2) + 4 * lh;
    O[(size_t)(m0 + mm) * 512 + n0 + wn + l31] = acc[r] + bv;
  }
}

// ---------------------------------------------------------------------------
// MFMA flash attention — R9: R8 pipeline (4-slot K ring, counted vmcnt) with
// coalesced-swizzled K staging. R8 post-mortem: depth-3 prefetch was NULL ->
// not latency-bound; theory is TA-transaction throughput (old stageK: 32
// half-used 64B txn per async16 from the 128B row stride). New stageK: 16
// fully-used txn per async16 (2x fewer, no overfetch); qkt reads carry the
// XOR, conflict-free. V path unchanged (reg dbuf).
// ---------------------------------------------------------------------------
__global__ __launch_bounds__(256, 2) void attn_mfma(const unsigned short* __restrict__ Q,
                                                    const unsigned short* __restrict__ K,
                                                    const unsigned short* __restrict__ VT,
                                                    unsigned short* __restrict__ O) {
  __shared__ __align__(16) unsigned short arena[4][8192];  // 16 KB/wave: K 4-slot ring
  __shared__ float larr[4][64];
  __shared__ float warr[4][64];

  const int tid = threadIdx.x;
  const int lane = tid & 63;
  const int w = tid >> 6;          // wave id = key quarter
  const int l31 = lane & 31, lh = lane >> 5;

  // XCD swizzle: pin 2 bh per XCD
  const int bid = blockIdx.x;
  const int g = bid & 7, j = bid >> 3;   // j in [0,64)
  const int bh = g * 2 + (j >> 5);
  const int qt = j & 31;                 // 32 q-tiles of 64 rows

  const unsigned short* Qh = Q + (size_t)bh * SEQ * HD;
  const unsigned short* Kh = K + (size_t)bh * SEQ * HD;
  const unsigned short* VTh = VT + (size_t)bh * HD * SEQ;

  s16x8 qf[2][4];
  #pragma unroll
  for (int q2 = 0; q2 < 2; q2++)
    #pragma unroll
    for (int t = 0; t < 4; t++)
      qf[q2][t] = *(const s16x8*)(Qh + (size_t)(qt * 64 + q2 * 32 + l31) * HD + 16 * t + 8 * lh);

  unsigned short* kbuf = &arena[w][0];  // 4 slots x 2048 ushorts
  const int kbase = w * 512;

  const int rl = lane >> 3;
  const int cl8 = ((lane & 7) ^ rl) * 8;
  const int x7 = l31 & 7;

  auto stageK = [&](int c, int slot) {
    // stripe tt: rows tt*8+rl of the 32x64 K tile, swizzled unit col
    const unsigned short* G = Kh + (size_t)(kbase + c * 32 + rl) * HD + cl8;
    #pragma unroll
    for (int tt = 0; tt < 4; tt++)
      async16(G + tt * 512, kbuf + slot * 2048 + tt * 512);
  };

  f32x16 scp[2];
  auto qkt = [&](int slot) {
    const unsigned short* kb = kbuf + slot * 2048 + l31 * 64;
    s16x8 kf[4];
    #pragma unroll
    for (int tt = 0; tt < 4; tt++)
      kf[tt] = *(const s16x8*)(kb + ((tt * 2 + lh) ^ x7) * 8);
    #pragma unroll
    for (int q2 = 0; q2 < 2; q2++) {
      f32x16 sc;
      #pragma unroll
      for (int r = 0; r < 16; r++) sc[r] = 0.f;
      #pragma unroll
      for (int tt = 0; tt < 4; tt++) sc = MFMA32(kf[tt], qf[q2][tt], sc);
      scp[q2] = sc;
    }
  };

  // ---------------- sweep 1: per-q l = sum(exp2(s)), 4-deep pipeline -----
  float lsum[2] = {0.f, 0.f};
  auto accum_l = [&]() {
    #pragma unroll
    for (int q2 = 0; q2 < 2; q2++) {
      float s0 = 0.f, s1 = 0.f, s2 = 0.f, s3 = 0.f;
      #pragma unroll
      for (int r = 0; r < 4; r++) {
        s0 += EXP2(scp[q2][r]);
        s1 += EXP2(scp[q2][4 + r]);
        s2 += EXP2(scp[q2][8 + r]);
        s3 += EXP2(scp[q2][12 + r]);
      }
      lsum[q2] += (s0 + s1) + (s2 + s3);
    }
  };

  stageK(0, 0);
  stageK(1, 1);
  stageK(2, 2);
  for (int c = 0; c < 16; ++c) {
    if (c + 3 < 16) stageK(c + 3, (c + 3) & 3);
    if (c > 0) accum_l();
    if (c < 13) { WAITVM12(); }
    else if (c == 13) { WAITVM8(); }
    else if (c == 14) { WAITVM4(); }
    else { WAITVM0(); }
    SB0();
    qkt(c & 3);
  }
  accum_l();
  #pragma unroll
  for (int q2 = 0; q2 < 2; q2++) lsum[q2] += __shfl_xor(lsum[q2], 32);
  if (lh == 0) { larr[w][l31] = lsum[0]; larr[w][32 + l31] = lsum[1]; }
  __syncthreads();
  float tl[2];
  #pragma unroll
  for (int q2 = 0; q2 < 2; q2++)
    tl[q2] = ATT_T * (larr[0][q2 * 32 + l31] + larr[1][q2 * 32 + l31] +
                      larr[2][q2 * 32 + l31] + larr[3][q2 * 32 + l31]);

  // ---------------- sweep 2: clip + PV, 4-deep K + 2-deep V ----------------
  f32x16 acc[2][2];
  #pragma unroll
  for (int q2 = 0; q2 < 2; q2++)
    #pragma unroll
    for (int dh = 0; dh < 2; dh++)
      #pragma unroll
      for (int r = 0; r < 16; r++) acc[q2][dh][r] = 0.f;
  float wacc[2] = {0.f, 0.f};
  s16x8 vrA[4], vrB[4];  // V dbuf in regs, statically indexed

  auto loadV = [&](int c, s16x8(&vr)[4]) {
    #pragma unroll
    for (int dh = 0; dh < 2; dh++)
      #pragma unroll
      for (int kc = 0; kc < 2; kc++)
        vr[dh * 2 + kc] = *(const s16x8*)(VTh + (size_t)(dh * 32 + l31) * SEQ +
                                          kbase + c * 32 + kc * 16 + lh * 8);
  };
  auto softmax_pv = [&](const s16x8(&vr)[4]) {
    s16x8 pf[2][2];
    #pragma unroll
    for (int q2 = 0; q2 < 2; q2++) {
      uint2 quads[4];
      #pragma unroll
      for (int gq = 0; gq < 4; gq++) {
        float u0 = fmaxf(EXP2(scp[q2][4 * gq + 0]) - tl[q2], 0.f);
        float u1 = fmaxf(EXP2(scp[q2][4 * gq + 1]) - tl[q2], 0.f);
        float u2 = fmaxf(EXP2(scp[q2][4 * gq + 2]) - tl[q2], 0.f);
        float u3 = fmaxf(EXP2(scp[q2][4 * gq + 3]) - tl[q2], 0.f);
        wacc[q2] += (u0 + u1) + (u2 + u3);
        quads[gq].x = permpack(u0, u1);
        quads[gq].y = permpack(u2, u3);
      }
      #pragma unroll
      for (int tp = 0; tp < 2; tp++) {
        unsigned x0, z0, x1, z1;
        plswap(quads[2 * tp].x, quads[2 * tp + 1].x, lh, x0, z0);
        plswap(quads[2 * tp].y, quads[2 * tp + 1].y, lh, x1, z1);
        uint4 fr;
        fr.x = x0; fr.y = x1; fr.z = z0; fr.w = z1;
        pf[q2][tp] = __builtin_bit_cast(s16x8, fr);
      }
    }
    #pragma unroll
    for (int q2 = 0; q2 < 2; q2++)
      #pragma unroll
      for (int dh = 0; dh < 2; dh++) {
        acc[q2][dh] = MFMA32(pf[q2][0], vr[dh * 2 + 0], acc[q2][dh]);
        acc[q2][dh] = MFMA32(pf[q2][1], vr[dh * 2 + 1], acc[q2][dh]);
      }
  };

  stageK(0, 0);
  stageK(1, 1);
  stageK(2, 2);
  loadV(0, vrA);
  for (int cc = 0; cc < 16; cc += 2) {
    // -------- even half i=cc: softmax chunk cc-1 (vrB), qkt(cc) --------
    if (cc > 0) {
      if (cc < 14) { WAITVM12(); } else { WAITVM8(); }
      SB0();
      softmax_pv(vrB);                  // chunk cc-1, uses V(cc-1)
    }
    loadV(cc + 1, vrB);
    if (cc + 3 < 16) stageK(cc + 3, (cc + 3) & 3);
    if (cc == 0) { WAITVM12(); }        // cold start: drains K0..K2
    SB0();
    qkt(cc & 3);
    // -------- odd half i=cc+1: softmax chunk cc (vrA), qkt(cc+1) --------
    if (cc == 0) { WAITVM8(); }         // drains V0
    else if (cc < 14) { WAITVM12(); }
    else { WAITVM4(); }
    SB0();
    softmax_pv(vrA);                    // chunk cc, uses V(cc)
    if (cc + 2 < 16) loadV(cc + 2, vrA);
    if (cc + 4 < 16) stageK(cc + 4, (cc + 4) & 3);
    SB0();
    qkt((cc + 1) & 3);
  }
  WAITVM0();
  SB0();
  softmax_pv(vrB);                      // chunk 15, uses V(15)

  // ---------------- cross-wave merge + output ----------------
  #pragma unroll
  for (int q2 = 0; q2 < 2; q2++) wacc[q2] += __shfl_xor(wacc[q2], 32);
  if (lh == 0) { warr[w][l31] = wacc[0]; warr[w][32 + l31] = wacc[1]; }
  __syncthreads();

  float* plane0 = (float*)&arena[0][0];  // 64x64 f32 = 16 KB (row 0)
  float* plane1 = (float*)&arena[1][0];  // row 1

  if (w >= 2) {
    float* pl = (w == 2) ? plane0 : plane1;
    #pragma unroll
    for (int q2 = 0; q2 < 2; q2++)
      #pragma unroll
      for (int dh = 0; dh < 2; dh++)
        #pragma unroll
        for (int r = 0; r < 16; r++) {
          int ql = q2 * 32 + (r & 3) + 8 * (r >> 2) + 4 * lh;
          pl[ql * 64 + dh * 32 + l31] = acc[q2][dh][r];
        }
  }
  __syncthreads();
  if (w < 2) {
    float* pl = (w == 0) ? plane0 : plane1;
    #pragma unroll
    for (int q2 = 0; q2 < 2; q2++)
      #pragma unroll
      for (int dh = 0; dh < 2; dh++)
        #pragma unroll
        for (int r = 0; r < 16; r++) {
          int ql = q2 * 32 + (r & 3) + 8 * (r >> 2) + 4 * lh;
          acc[q2][dh][r] += pl[ql * 64 + dh * 32 + l31];
        }
  }
  __syncthreads();
  if (w == 1) {
    #pragma unroll
    for (int q2 = 0; q2 < 2; q2++)
      #pragma unroll
      for (int dh = 0; dh < 2; dh++)
        #pragma unroll
        for (int r = 0; r < 16; r++) {
          int ql = q2 * 32 + (r & 3) + 8 * (r >> 2) + 4 * lh;
          plane0[ql * 64 + dh * 32 + l31] = acc[q2][dh][r];
        }
  }
  __syncthreads();
  unsigned short* otile = &arena[2][0];  // 64x64 bf16 = 8 KB (row 2)
  if (w == 0) {
    #pragma unroll
    for (int q2 = 0; q2 < 2; q2++)
      #pragma unroll
      for (int dh = 0; dh < 2; dh++)
        #pragma unroll
        for (int r = 0; r < 16; r++) {
          int ql = q2 * 32 + (r & 3) + 8 * (r >> 2) + 4 * lh;
          float wt = warr[0][ql] + warr[1][ql] + warr[2][ql] + warr[3][ql];
          float v = (acc[q2][dh][r] + plane0[ql * 64 + dh * 32 + l31]) / wt;
          otile[ql * 64 + dh * 32 + l31] = bfr(v);
        }
  }
  __syncthreads();
  const int b = bh >> 3, h = bh & 7;
  #pragma unroll
  for (int it = 0; it < 2; ++it) {
    int c2 = tid + it * 256;
    int mm = c2 >> 3, seg = c2 & 7;
    uint4 vdat = *(const uint4*)(otile + mm * 64 + seg * 8);
    *(uint4*)(O + ((size_t)(b * SEQ + qt * 64 + mm)) * 512 + h * HD + seg * 8) = vdat;
  }
}

// ---------------------------------------------------------------------------
extern "C" void kernel_launch(void* const* d_in, const int* in_sizes, int n_in,
                              void* d_out, int out_size, void* d_ws, size_t ws_size,
                              hipStream_t stream) {
  const float* fr = (const float*)d_in[0];
  const float* dt = (const float*)d_in[1];
  const float* Wq = (const float*)d_in[2];
  const float* Wk = (const float*)d_in[3];
  const float* Wv = (const float*)d_in[4];
  const float* Wo = (const float*)d_in[5];
  const float* bo = (const float*)d_in[6];
  float* out = (float*)d_out;

  const size_t planeE = (size_t)BB * SEQ * 512;  // 2,097,152 elements
  const size_t wE = 512 * 512;
  unsigned short* p = (unsigned short*)d_ws;
  unsigned short* WqT = p; p += wE;
  unsigned short* WkT = p; p += wE;
  unsigned short* WvT = p; p += wE;
  unsigned short* WoT = p; p += wE;
  unsigned short* Qp  = p; p += planeE;
  unsigned short* Kp  = p; p += planeE;
  unsigned short* VTp = p; p += planeE;
  unsigned short* aoB = p; p += planeE;

  // bf16 copies of fr/dt live in d_out (8.4 MB = exactly out_size); they are
  // fully consumed by gemm_qkv before gemm_out overwrites d_out with the
  // final fp32 result.
  unsigned short* frB = (unsigned short*)d_out;
  unsigned short* dtB = (unsigned short*)d_out + planeE;

  prep<<<2304, 256, 0, stream>>>(fr, dt, Wq, Wk, Wv, Wo, frB, dtB, WqT, WkT, WvT, WoT);

  gemm_qkv<<<dim3(4, 64, 3), 256, 0, stream>>>(frB, dtB, WqT, WkT, WvT, Qp, Kp, VTp);

  attn_mfma<<<BB * NHEAD * 32, 256, 0, stream>>>(Qp, Kp, VTp, aoB);

  gemm_out<<<dim3(8, 64), 256, 0, stream>>>(aoB, WoT, bo, out);
}

// Round 10
// 136.297 us; speedup vs baseline: 1.2039x; 1.0507x over previous
//
#include <hip/hip_runtime.h>
#include <hip/hip_bf16.h>

#define BB 2
#define SEQ 2048
#define NHEAD 8
#define HD 64
#define ATT_T 1e-4f
#define QSCALE 0.18033688011112042f  // 0.125 * log2(e): scores in log2 domain

typedef short s16x8 __attribute__((ext_vector_type(8)));
typedef float f32x16 __attribute__((ext_vector_type(16)));

#define MFMA32(a, b, c) __builtin_amdgcn_mfma_f32_32x32x16_bf16((a), (b), (c), 0, 0, 0)
#define EXP2(x) __builtin_amdgcn_exp2f(x)
#define SB0() __builtin_amdgcn_sched_barrier(0)
// s_waitcnt imm: vmcnt[3:0]=bits3:0, expcnt=bits6:4, lgkmcnt=bits11:8, vmcnt[5:4]=bits15:14
#define WAITVM0() __builtin_amdgcn_s_waitcnt(0x0F70)
#define WAITVM4() __builtin_amdgcn_s_waitcnt(0x0F74)
#define WAITVM8() __builtin_amdgcn_s_waitcnt(0x0F78)
#define WAITVM12() __builtin_amdgcn_s_waitcnt(0x0F7C)

__device__ __forceinline__ unsigned short bfr(float x) {
  __hip_bfloat16 h = __float2bfloat16(x);
  return __builtin_bit_cast(unsigned short, h);
}
__device__ __forceinline__ unsigned int packbf(float a, float b) {
  return (unsigned int)bfr(a) | ((unsigned int)bfr(b) << 16);
}
// 1-op truncating bf16 pack of two fp32 (v_perm_b32)
__device__ __forceinline__ unsigned int permpack(float a, float b) {
  return __builtin_amdgcn_perm(__builtin_bit_cast(unsigned int, b),
                               __builtin_bit_cast(unsigned int, a), 0x07060302u);
}
__device__ __forceinline__ void async16(const void* g, void* l) {
  __builtin_amdgcn_global_load_lds(
      (const __attribute__((address_space(1))) unsigned int*)g,
      (__attribute__((address_space(3))) unsigned int*)l, 16, 0, 0);
}
// half-wave exchange: x = (lh?partner(b):a), z = (lh?b:partner(a)) in one op
__device__ __forceinline__ void plswap(unsigned a, unsigned b, int lh,
                                       unsigned& x, unsigned& z) {
#if __has_builtin(__builtin_amdgcn_permlane32_swap)
  typedef unsigned uint2v __attribute__((ext_vector_type(2)));
  uint2v r = __builtin_amdgcn_permlane32_swap(a, b, false, false);
  x = r[0];
  z = r[1];
#else
  unsigned ea = (unsigned)__shfl_xor((int)a, 32);
  unsigned eb = (unsigned)__shfl_xor((int)b, 32);
  x = lh ? eb : a;
  z = lh ? b : ea;
#endif
}

// ---------------------------------------------------------------------------
// R10 layouts: Q/K/V are stored PRE-BLOCKED in fragment order so attn's
// global->LDS staging is contiguous (16 fully-used txn/instr, R9's win) AND
// LDS fragment reads are contiguous (R8's zero-conflict read — R9's 1.05M
// bank conflicts came from the XOR-scattered read).
//   Q/K: [bh][chunk=s/32][unit v=tt*64+lh*32+l31]*8shorts
//        holds row l31(+32*chunk), cols tt*16+lh*8..+8
//   V:   [bh][kchunk=k/32][unit v=(dh*2+kc)*64+lh*32+l31]*8
//        holds VT[dh*32+l31][kchunk*32+kc*16+lh*8..+8]
// Verified by element trace: K[5][9]->short297, V[d9][k37]->2125, Q[70][25]
// ->4913 on both producer and consumer sides.
// ---------------------------------------------------------------------------

// ---------------------------------------------------------------------------
// prep: fused pre-pass (unchanged, passed).
// ---------------------------------------------------------------------------
__global__ __launch_bounds__(256) void prep(const float* __restrict__ fr,
                                            const float* __restrict__ dt,
                                            const float* __restrict__ w0,
                                            const float* __restrict__ w1,
                                            const float* __restrict__ w2,
                                            const float* __restrict__ w3,
                                            unsigned short* __restrict__ frB,
                                            unsigned short* __restrict__ dtB,
                                            unsigned short* __restrict__ o0,
                                            unsigned short* __restrict__ o1,
                                            unsigned short* __restrict__ o2,
                                            unsigned short* __restrict__ o3) {
  const int bid = blockIdx.x;
  if (bid < 2048) {
    const float* src = (bid < 1024) ? fr : dt;
    unsigned short* dst = (bid < 1024) ? frB : dtB;
    const int chunk = (bid < 1024) ? bid : bid - 1024;
    const size_t base = (size_t)chunk * 2048 + threadIdx.x * 8;
    float4 a = *(const float4*)(src + base);
    float4 b = *(const float4*)(src + base + 4);
    uint4 o;
    o.x = packbf(a.x, a.y);
    o.y = packbf(a.z, a.w);
    o.z = packbf(b.x, b.y);
    o.w = packbf(b.z, b.w);
    *(uint4*)(dst + base) = o;
    return;
  }
  // ---- weight transpose tiles ----
  __shared__ float tle[64][65];
  const int t = bid - 2048;
  const int z = t >> 6, by = (t >> 3) & 7, bx = t & 7;
  const float* W = z == 0 ? w0 : z == 1 ? w1 : z == 2 ? w2 : w3;
  unsigned short* WT = z == 0 ? o0 : z == 1 ? o1 : z == 2 ? o2 : o3;
  const int r0 = by * 64, c0 = bx * 64;
  const int tr = threadIdx.x >> 4;
  const int tc = threadIdx.x & 15;
  #pragma unroll
  for (int i = 0; i < 4; i++) {
    int r = tr + i * 16;
    float4 v = *(const float4*)(W + (size_t)(r0 + r) * 512 + c0 + tc * 4);
    tle[r][tc * 4 + 0] = v.x;
    tle[r][tc * 4 + 1] = v.y;
    tle[r][tc * 4 + 2] = v.z;
    tle[r][tc * 4 + 3] = v.w;
  }
  __syncthreads();
  #pragma unroll
  for (int i = 0; i < 4; i++) {
    int c = tr + i * 16;
    int rr = tc * 4;
    uint2 p;
    p.x = packbf(tle[rr + 0][c], tle[rr + 1][c]);
    p.y = packbf(tle[rr + 2][c], tle[rr + 3][c]);
    *(uint2*)(WT + (size_t)(c0 + c) * 512 + r0 + rr) = p;
  }
}

// ---------------------------------------------------------------------------
// Fused Q/K/V projection GEMM — R10: main loop = R9 (coalesced-swizzled
// staging); epilogues write the BLOCKED layouts above (coalesced: 256
// consecutive threads -> contiguous 4KB runs).
// ---------------------------------------------------------------------------
__global__ __launch_bounds__(256) void gemm_qkv(const unsigned short* __restrict__ frB,
                                                const unsigned short* __restrict__ dtB,
                                                const unsigned short* __restrict__ WqT,
                                                const unsigned short* __restrict__ WkT,
                                                const unsigned short* __restrict__ WvT,
                                                unsigned short* __restrict__ Qp,
                                                unsigned short* __restrict__ Kp,
                                                unsigned short* __restrict__ VTp) {
  __shared__ __align__(16) unsigned short smem[24576];  // A 2x4096 | B 2x8192 (48 KB)
  unsigned short* Asm = smem;
  unsigned short* Bsm = smem + 8192;
  const int tid = threadIdx.x, lane = tid & 63, w = tid >> 6;
  const int l31 = lane & 31, lh = lane >> 5;
  const int m0 = blockIdx.y * 64, n0 = blockIdx.x * 128;
  const int z = blockIdx.z;
  const unsigned short* Ab = z == 0 ? frB : dtB;
  const unsigned short* BT = z == 0 ? WqT : (z == 1 ? WkT : WvT);
  unsigned short* OP = z == 0 ? Qp : (z == 1 ? Kp : VTp);
  const float scale = z == 0 ? QSCALE : 1.0f;

  const int rl = lane >> 3;                       // row within stripe
  const int cl8 = ((lane & 7) ^ rl) * 8;          // swizzled 16B-unit, in shorts
  const int x7 = l31 & 7;

  auto stage = [&](int kt, int buf) {
    const int k0 = kt * 64;
    #pragma unroll
    for (int i = 0; i < 2; i++) {
      int s = w * 2 + i;                          // A stripe 0..7 (64 rows)
      async16(Ab + (size_t)(m0 + s * 8 + rl) * 512 + k0 + cl8,
              Asm + buf * 4096 + s * 512);
    }
    #pragma unroll
    for (int i = 0; i < 4; i++) {
      int s = w * 4 + i;                          // B stripe 0..15 (128 rows)
      async16(BT + (size_t)(n0 + s * 8 + rl) * 512 + k0 + cl8,
              Bsm + buf * 8192 + s * 512);
    }
  };

  f32x16 acc[2];
  #pragma unroll
  for (int j = 0; j < 2; j++)
    #pragma unroll
    for (int r = 0; r < 16; r++) acc[j][r] = 0.f;

  stage(0, 0);
  for (int kt = 0; kt < 8; ++kt) {
    __syncthreads();
    if (kt + 1 < 8) stage(kt + 1, (kt + 1) & 1);
    const int buf = kt & 1;
    const unsigned short* as = Asm + buf * 4096 + ((w & 1) * 32 + l31) * 64;
    const unsigned short* bs = Bsm + buf * 8192 + ((w >> 1) * 64 + l31) * 64;
    #pragma unroll
    for (int ks = 0; ks < 4; ++ks) {
      const int co = ((ks * 2 + lh) ^ x7) * 8;
      s16x8 af = *(const s16x8*)(as + co);
      s16x8 b0 = *(const s16x8*)(bs + co);
      s16x8 b1 = *(const s16x8*)(bs + 2048 + co);
      acc[0] = MFMA32(af, b0, acc[0]);
      acc[1] = MFMA32(af, b1, acc[1]);
    }
  }

  const int wm = (w & 1) * 32, wn = (w >> 1) * 64;
  const int bb = m0 >> 11, s0 = m0 & 2047;
  const int h0 = n0 >> 6, cbase = s0 >> 5;
  __syncthreads();
  if (z <= 1) {
    #pragma unroll
    for (int j = 0; j < 2; j++)
      #pragma unroll
      for (int r = 0; r < 16; r++) {
        int mm = wm + (r & 3) + 8 * (r >> 2) + 4 * lh;
        int nn = wn + j * 32 + l31;
        smem[mm * 136 + nn] = bfr(acc[j][r] * scale);
      }
    __syncthreads();
    // blocked writer: unit u -> (h'=b>>1, c'=b&1, v): tt=v>>6, lhv=(v>>5)&1,
    // lv=v&31; src smem[row=c'*32+lv][col=h'*64+tt*16+lhv*8]
    #pragma unroll
    for (int it = 0; it < 4; ++it) {
      int u = tid + it * 256;
      int b = u >> 8, v = u & 255;
      int hp = b >> 1, cp = b & 1;
      int mm = cp * 32 + (v & 31);
      int nn = hp * 64 + ((v >> 6) << 4) + (((v >> 5) & 1) << 3);
      uint4 vdat = *(const uint4*)(smem + mm * 136 + nn);
      *(uint4*)(OP + ((size_t)(bb * NHEAD + h0 + hp)) * SEQ * HD +
                (size_t)(cbase + cp) * 2048 + v * 8) = vdat;
    }
  } else {
    #pragma unroll
    for (int j = 0; j < 2; j++)
      #pragma unroll
      for (int r = 0; r < 16; r += 2) {
        int mm = wm + (r & 3) + 8 * (r >> 2) + 4 * lh;  // even
        int nn = wn + j * 32 + l31;
        *(unsigned int*)(smem + nn * 72 + mm) = packbf(acc[j][r], acc[j][r + 1]);
      }
    __syncthreads();
    // blocked V writer: u -> (h'=u>>9, c'=(u>>8)&1, v): dh=v>>7, kc=(v>>6)&1,
    // lhv=(v>>5)&1, lv=v&31; src smem[nn=h'*64+dh*32+lv][mm0=c'*32+kc*16+lhv*8]
    #pragma unroll
    for (int it = 0; it < 4; ++it) {
      int u = tid + it * 256;
      int hp = u >> 9;
      int rem = u & 511;
      int cp = rem >> 8, v = rem & 255;
      int nn = hp * 64 + ((v >> 7) << 5) + (v & 31);
      int mm0 = cp * 32 + (((v >> 6) & 1) << 4) + (((v >> 5) & 1) << 3);
      uint4 vdat = *(const uint4*)(smem + nn * 72 + mm0);
      *(uint4*)(OP + ((size_t)(bb * NHEAD + h0 + hp)) * SEQ * HD +
                (size_t)(cbase + cp) * 2048 + v * 8) = vdat;
    }
  }
}

// ---------------------------------------------------------------------------
// Final projection — R9 form (coalesced-swizzled staging), unchanged.
// ---------------------------------------------------------------------------
__global__ __launch_bounds__(256) void gemm_out(const unsigned short* __restrict__ A,
                                                const unsigned short* __restrict__ BT,
                                                const float* __restrict__ bias,
                                                float* __restrict__ O) {
  __shared__ __align__(16) unsigned short smem[16384];  // A 2x4096 | B 2x4096
  unsigned short* Asm = smem;
  unsigned short* Bsm = smem + 8192;
  const int tid = threadIdx.x, lane = tid & 63, w = tid >> 6;
  const int l31 = lane & 31, lh = lane >> 5;
  const int m0 = blockIdx.y * 64, n0 = blockIdx.x * 64;

  const int rl = lane >> 3;
  const int cl8 = ((lane & 7) ^ rl) * 8;
  const int x7 = l31 & 7;

  auto stage = [&](int kt, int buf) {
    const int k0 = kt * 64;
    #pragma unroll
    for (int i = 0; i < 2; i++) {
      int s = w * 2 + i;
      async16(A + (size_t)(m0 + s * 8 + rl) * 512 + k0 + cl8,
              Asm + buf * 4096 + s * 512);
      async16(BT + (size_t)(n0 + s * 8 + rl) * 512 + k0 + cl8,
              Bsm + buf * 4096 + s * 512);
    }
  };

  f32x16 acc;
  #pragma unroll
  for (int r = 0; r < 16; r++) acc[r] = 0.f;

  stage(0, 0);
  for (int kt = 0; kt < 8; ++kt) {
    __syncthreads();
    if (kt + 1 < 8) stage(kt + 1, (kt + 1) & 1);
    const int buf = kt & 1;
    const unsigned short* as = Asm + buf * 4096 + ((w & 1) * 32 + l31) * 64;
    const unsigned short* bs = Bsm + buf * 4096 + ((w >> 1) * 32 + l31) * 64;
    #pragma unroll
    for (int ks = 0; ks < 4; ++ks) {
      const int co = ((ks * 2 + lh) ^ x7) * 8;
      s16x8 af = *(const s16x8*)(as + co);
      s16x8 bf = *(const s16x8*)(bs + co);
      acc = MFMA32(af, bf, acc);
    }
  }

  const int wm = (w & 1) * 32, wn = (w >> 1) * 32;
  float bv = bias[n0 + wn + l31];
  #pragma unroll
  for (int r = 0; r < 16; r++) {
    int mm = wm + (r & 3) + 8 * (r >> 2) + 4 * lh;
    O[(size_t)(m0 + mm) * 512 + n0 + wn + l31] = acc[r] + bv;
  }
}

// ---------------------------------------------------------------------------
// MFMA flash attention — R10: R8/R9 pipeline (4-slot K ring, counted vmcnt),
// but Q/K/V consumed from the pre-blocked layouts: stageK/loadV/qf are all
// CONTIGUOUS 1KB per instruction (16 fully-used txn) and qkt reads revert to
// the R8 contiguous fragment read (zero bank conflicts). V reg-dbuf kept.
// ---------------------------------------------------------------------------
__global__ __launch_bounds__(256, 2) void attn_mfma(const unsigned short* __restrict__ Q,
                                                    const unsigned short* __restrict__ K,
                                                    const unsigned short* __restrict__ VT,
                                                    unsigned short* __restrict__ O) {
  __shared__ __align__(16) unsigned short arena[4][8192];  // 16 KB/wave: K 4-slot ring
  __shared__ float larr[4][64];
  __shared__ float warr[4][64];

  const int tid = threadIdx.x;
  const int lane = tid & 63;
  const int w = tid >> 6;          // wave id = key quarter
  const int l31 = lane & 31, lh = lane >> 5;

  // XCD swizzle: pin 2 bh per XCD
  const int bid = blockIdx.x;
  const int g = bid & 7, j = bid >> 3;   // j in [0,64)
  const int bh = g * 2 + (j >> 5);
  const int qt = j & 31;                 // 32 q-tiles of 64 rows

  const unsigned short* Qh = Q + (size_t)bh * SEQ * HD;
  const unsigned short* Kh = K + (size_t)bh * SEQ * HD;
  const unsigned short* VTh = VT + (size_t)bh * SEQ * HD;

  s16x8 qf[2][4];
  #pragma unroll
  for (int q2 = 0; q2 < 2; q2++)
    #pragma unroll
    for (int t = 0; t < 4; t++)
      qf[q2][t] = *(const s16x8*)(Qh + (size_t)(qt * 2 + q2) * 2048 + t * 512 + lane * 8);

  unsigned short* kbuf = &arena[w][0];  // 4 slots x 2048 ushorts

  auto stageK = [&](int c, int slot) {
    const unsigned short* G = Kh + (size_t)(w * 16 + c) * 2048 + lane * 8;
    #pragma unroll
    for (int tt = 0; tt < 4; tt++)
      async16(G + tt * 512, kbuf + slot * 2048 + tt * 512);
  };

  f32x16 scp[2];
  auto qkt = [&](int slot) {
    s16x8 kf[4];
    #pragma unroll
    for (int tt = 0; tt < 4; tt++)
      kf[tt] = *(const s16x8*)(kbuf + slot * 2048 + tt * 512 + lane * 8);
    #pragma unroll
    for (int q2 = 0; q2 < 2; q2++) {
      f32x16 sc;
      #pragma unroll
      for (int r = 0; r < 16; r++) sc[r] = 0.f;
      #pragma unroll
      for (int tt = 0; tt < 4; tt++) sc = MFMA32(kf[tt], qf[q2][tt], sc);
      scp[q2] = sc;
    }
  };

  // ---------------- sweep 1: per-q l = sum(exp2(s)), 4-deep pipeline -----
  float lsum[2] = {0.f, 0.f};
  auto accum_l = [&]() {
    #pragma unroll
    for (int q2 = 0; q2 < 2; q2++) {
      float s0 = 0.f, s1 = 0.f, s2 = 0.f, s3 = 0.f;
      #pragma unroll
      for (int r = 0; r < 4; r++) {
        s0 += EXP2(scp[q2][r]);
        s1 += EXP2(scp[q2][4 + r]);
        s2 += EXP2(scp[q2][8 + r]);
        s3 += EXP2(scp[q2][12 + r]);
      }
      lsum[q2] += (s0 + s1) + (s2 + s3);
    }
  };

  stageK(0, 0);
  stageK(1, 1);
  stageK(2, 2);
  for (int c = 0; c < 16; ++c) {
    if (c + 3 < 16) stageK(c + 3, (c + 3) & 3);
    if (c > 0) accum_l();
    if (c < 13) { WAITVM12(); }
    else if (c == 13) { WAITVM8(); }
    else if (c == 14) { WAITVM4(); }
    else { WAITVM0(); }
    SB0();
    qkt(c & 3);
  }
  accum_l();
  #pragma unroll
  for (int q2 = 0; q2 < 2; q2++) lsum[q2] += __shfl_xor(lsum[q2], 32);
  if (lh == 0) { larr[w][l31] = lsum[0]; larr[w][32 + l31] = lsum[1]; }
  __syncthreads();
  float tl[2];
  #pragma unroll
  for (int q2 = 0; q2 < 2; q2++)
    tl[q2] = ATT_T * (larr[0][q2 * 32 + l31] + larr[1][q2 * 32 + l31] +
                      larr[2][q2 * 32 + l31] + larr[3][q2 * 32 + l31]);

  // ---------------- sweep 2: clip + PV, 4-deep K + 2-deep V ----------------
  f32x16 acc[2][2];
  #pragma unroll
  for (int q2 = 0; q2 < 2; q2++)
    #pragma unroll
    for (int dh = 0; dh < 2; dh++)
      #pragma unroll
      for (int r = 0; r < 16; r++) acc[q2][dh][r] = 0.f;
  float wacc[2] = {0.f, 0.f};
  s16x8 vrA[4], vrB[4];  // V dbuf in regs, statically indexed

  auto loadV = [&](int c, s16x8(&vr)[4]) {
    const unsigned short* G = VTh + (size_t)(w * 16 + c) * 2048 + lane * 8;
    #pragma unroll
    for (int jj = 0; jj < 4; jj++)
      vr[jj] = *(const s16x8*)(G + jj * 512);
  };
  auto softmax_pv = [&](const s16x8(&vr)[4]) {
    s16x8 pf[2][2];
    #pragma unroll
    for (int q2 = 0; q2 < 2; q2++) {
      uint2 quads[4];
      #pragma unroll
      for (int gq = 0; gq < 4; gq++) {
        float u0 = fmaxf(EXP2(scp[q2][4 * gq + 0]) - tl[q2], 0.f);
        float u1 = fmaxf(EXP2(scp[q2][4 * gq + 1]) - tl[q2], 0.f);
        float u2 = fmaxf(EXP2(scp[q2][4 * gq + 2]) - tl[q2], 0.f);
        float u3 = fmaxf(EXP2(scp[q2][4 * gq + 3]) - tl[q2], 0.f);
        wacc[q2] += (u0 + u1) + (u2 + u3);
        quads[gq].x = permpack(u0, u1);
        quads[gq].y = permpack(u2, u3);
      }
      #pragma unroll
      for (int tp = 0; tp < 2; tp++) {
        unsigned x0, z0, x1, z1;
        plswap(quads[2 * tp].x, quads[2 * tp + 1].x, lh, x0, z0);
        plswap(quads[2 * tp].y, quads[2 * tp + 1].y, lh, x1, z1);
        uint4 fr;
        fr.x = x0; fr.y = x1; fr.z = z0; fr.w = z1;
        pf[q2][tp] = __builtin_bit_cast(s16x8, fr);
      }
    }
    #pragma unroll
    for (int q2 = 0; q2 < 2; q2++)
      #pragma unroll
      for (int dh = 0; dh < 2; dh++) {
        acc[q2][dh] = MFMA32(pf[q2][0], vr[dh * 2 + 0], acc[q2][dh]);
        acc[q2][dh] = MFMA32(pf[q2][1], vr[dh * 2 + 1], acc[q2][dh]);
      }
  };

  stageK(0, 0);
  stageK(1, 1);
  stageK(2, 2);
  loadV(0, vrA);
  for (int cc = 0; cc < 16; cc += 2) {
    // -------- even half i=cc: softmax chunk cc-1 (vrB), qkt(cc) --------
    if (cc > 0) {
      if (cc < 14) { WAITVM12(); } else { WAITVM8(); }
      SB0();
      softmax_pv(vrB);                  // chunk cc-1, uses V(cc-1)
    }
    loadV(cc + 1, vrB);
    if (cc + 3 < 16) stageK(cc + 3, (cc + 3) & 3);
    if (cc == 0) { WAITVM12(); }        // cold start: drains K0..K2
    SB0();
    qkt(cc & 3);
    // -------- odd half i=cc+1: softmax chunk cc (vrA), qkt(cc+1) --------
    if (cc == 0) { WAITVM8(); }         // drains V0
    else if (cc < 14) { WAITVM12(); }
    else { WAITVM4(); }
    SB0();
    softmax_pv(vrA);                    // chunk cc, uses V(cc)
    if (cc + 2 < 16) loadV(cc + 2, vrA);
    if (cc + 4 < 16) stageK(cc + 4, (cc + 4) & 3);
    SB0();
    qkt((cc + 1) & 3);
  }
  WAITVM0();
  SB0();
  softmax_pv(vrB);                      // chunk 15, uses V(15)

  // ---------------- cross-wave merge + output ----------------
  #pragma unroll
  for (int q2 = 0; q2 < 2; q2++) wacc[q2] += __shfl_xor(wacc[q2], 32);
  if (lh == 0) { warr[w][l31] = wacc[0]; warr[w][32 + l31] = wacc[1]; }
  __syncthreads();

  float* plane0 = (float*)&arena[0][0];  // 64x64 f32 = 16 KB (row 0)
  float* plane1 = (float*)&arena[1][0];  // row 1

  if (w >= 2) {
    float* pl = (w == 2) ? plane0 : plane1;
    #pragma unroll
    for (int q2 = 0; q2 < 2; q2++)
      #pragma unroll
      for (int dh = 0; dh < 2; dh++)
        #pragma unroll
        for (int r = 0; r < 16; r++) {
          int ql = q2 * 32 + (r & 3) + 8 * (r >> 2) + 4 * lh;
          pl[ql * 64 + dh * 32 + l31] = acc[q2][dh][r];
        }
  }
  __syncthreads();
  if (w < 2) {
    float* pl = (w == 0) ? plane0 : plane1;
    #pragma unroll
    for (int q2 = 0; q2 < 2; q2++)
      #pragma unroll
      for (int dh = 0; dh < 2; dh++)
        #pragma unroll
        for (int r = 0; r < 16; r++) {
          int ql = q2 * 32 + (r & 3) + 8 * (r >> 2) + 4 * lh;
          acc[q2][dh][r] += pl[ql * 64 + dh * 32 + l31];
        }
  }
  __syncthreads();
  if (w == 1) {
    #pragma unroll
    for (int q2 = 0; q2 < 2; q2++)
      #pragma unroll
      for (int dh = 0; dh < 2; dh++)
        #pragma unroll
        for (int r = 0; r < 16; r++) {
          int ql = q2 * 32 + (r & 3) + 8 * (r >> 2) + 4 * lh;
          plane0[ql * 64 + dh * 32 + l31] = acc[q2][dh][r];
        }
  }
  __syncthreads();
  unsigned short* otile = &arena[2][0];  // 64x64 bf16 = 8 KB (row 2)
  if (w == 0) {
    #pragma unroll
    for (int q2 = 0; q2 < 2; q2++)
      #pragma unroll
      for (int dh = 0; dh < 2; dh++)
        #pragma unroll
        for (int r = 0; r < 16; r++) {
          int ql = q2 * 32 + (r & 3) + 8 * (r >> 2) + 4 * lh;
          float wt = warr[0][ql] + warr[1][ql] + warr[2][ql] + warr[3][ql];
          float v = (acc[q2][dh][r] + plane0[ql * 64 + dh * 32 + l31]) / wt;
          otile[ql * 64 + dh * 32 + l31] = bfr(v);
        }
  }
  __syncthreads();
  const int b = bh >> 3, h = bh & 7;
  #pragma unroll
  for (int it = 0; it < 2; ++it) {
    int c2 = tid + it * 256;
    int mm = c2 >> 3, seg = c2 & 7;
    uint4 vdat = *(const uint4*)(otile + mm * 64 + seg * 8);
    *(uint4*)(O + ((size_t)(b * SEQ + qt * 64 + mm)) * 512 + h * HD + seg * 8) = vdat;
  }
}

// ---------------------------------------------------------------------------
extern "C" void kernel_launch(void* const* d_in, const int* in_sizes, int n_in,
                              void* d_out, int out_size, void* d_ws, size_t ws_size,
                              hipStream_t stream) {
  const float* fr = (const float*)d_in[0];
  const float* dt = (const float*)d_in[1];
  const float* Wq = (const float*)d_in[2];
  const float* Wk = (const float*)d_in[3];
  const float* Wv = (const float*)d_in[4];
  const float* Wo = (const float*)d_in[5];
  const float* bo = (const float*)d_in[6];
  float* out = (float*)d_out;

  const size_t planeE = (size_t)BB * SEQ * 512;  // 2,097,152 elements
  const size_t wE = 512 * 512;
  unsigned short* p = (unsigned short*)d_ws;
  unsigned short* WqT = p; p += wE;
  unsigned short* WkT = p; p += wE;
  unsigned short* WvT = p; p += wE;
  unsigned short* WoT = p; p += wE;
  unsigned short* Qp  = p; p += planeE;
  unsigned short* Kp  = p; p += planeE;
  unsigned short* VTp = p; p += planeE;
  unsigned short* aoB = p; p += planeE;

  // bf16 copies of fr/dt live in d_out (8.4 MB = exactly out_size); they are
  // fully consumed by gemm_qkv before gemm_out overwrites d_out with the
  // final fp32 result.
  unsigned short* frB = (unsigned short*)d_out;
  unsigned short* dtB = (unsigned short*)d_out + planeE;

  prep<<<2304, 256, 0, stream>>>(fr, dt, Wq, Wk, Wv, Wo, frB, dtB, WqT, WkT, WvT, WoT);

  gemm_qkv<<<dim3(4, 64, 3), 256, 0, stream>>>(frB, dtB, WqT, WkT, WvT, Qp, Kp, VTp);

  attn_mfma<<<BB * NHEAD * 32, 256, 0, stream>>>(Qp, Kp, VTp, aoB);

  gemm_out<<<dim3(8, 64), 256, 0, stream>>>(aoB, WoT, bo, out);
}